// Round 1
// baseline (1715.038 us; speedup 1.0000x reference)
//
#include <hip/hip_runtime.h>
#include <hip/hip_bf16.h>
#include <math.h>

#define BATCH   512
#define IN_DIM  4096
#define HID_DIM 8192
#define OUT_DIM 1024
#define T_STEPS 10
#define LEAK    0.95f
#define ADAPT   0.02f

// ---------------------------------------------------------------------------
// r_in = sigmoid(x), vectorized float4
// ---------------------------------------------------------------------------
__global__ __launch_bounds__(256) void rates_kernel(const float* __restrict__ x,
                                                    float* __restrict__ r, int n4) {
    int i = blockIdx.x * blockDim.x + threadIdx.x;
    if (i >= n4) return;
    float4 v = ((const float4*)x)[i];
    float4 o;
    o.x = 1.f / (1.f + __expf(-v.x));
    o.y = 1.f / (1.f + __expf(-v.y));
    o.z = 1.f / (1.f + __expf(-v.z));
    o.w = 1.f / (1.f + __expf(-v.w));
    ((float4*)r)[i] = o;
}

// ---------------------------------------------------------------------------
// fp32 tiled GEMM: C[M,N] = A[M,K] @ B[K,N], row-major.
// 64x64 tile, BK=16, 256 threads, 4x4 micro-tile per thread.
// TRANS_OUT: write C transposed as CT[N,M] (for the tiny output-dyn kernel).
// ---------------------------------------------------------------------------
template <bool TRANS_OUT>
__global__ __launch_bounds__(256) void gemm_f32(const float* __restrict__ A,
                                                const float* __restrict__ B,
                                                float* __restrict__ C,
                                                int M, int N, int K) {
    const int BK = 16;
    __shared__ float As[BK][64 + 4];  // pad 4: 2-way max on stores, 16B-aligned reads
    __shared__ float Bs[BK][64];

    const int bx = blockIdx.x;        // N tile
    const int by = blockIdx.y;        // M tile
    const int tid = threadIdx.x;
    const int tcol = tid & 15;        // 0..15
    const int trow = tid >> 4;        // 0..15

    const int a_r = tid >> 2;         // 0..63
    const int a_c = (tid & 3) << 2;   // 0,4,8,12
    const int b_r = tid >> 4;         // 0..15
    const int b_c = (tid & 15) << 2;  // 0..60

    const float* Aptr = A + (size_t)(by * 64 + a_r) * K + a_c;
    const float* Bptr = B + (size_t)b_r * N + bx * 64 + b_c;

    float acc[4][4] = {};

    for (int k0 = 0; k0 < K; k0 += BK) {
        float4 av = *(const float4*)(Aptr + k0);
        float4 bv = *(const float4*)(Bptr + (size_t)k0 * N);
        __syncthreads();
        As[a_c + 0][a_r] = av.x;
        As[a_c + 1][a_r] = av.y;
        As[a_c + 2][a_r] = av.z;
        As[a_c + 3][a_r] = av.w;
        *(float4*)&Bs[b_r][b_c] = bv;
        __syncthreads();
#pragma unroll
        for (int kk = 0; kk < BK; ++kk) {
            float4 a = *(const float4*)&As[kk][trow * 4];
            float4 b = *(const float4*)&Bs[kk][tcol * 4];
            acc[0][0] += a.x * b.x; acc[0][1] += a.x * b.y; acc[0][2] += a.x * b.z; acc[0][3] += a.x * b.w;
            acc[1][0] += a.y * b.x; acc[1][1] += a.y * b.y; acc[1][2] += a.y * b.z; acc[1][3] += a.y * b.w;
            acc[2][0] += a.z * b.x; acc[2][1] += a.z * b.y; acc[2][2] += a.z * b.z; acc[2][3] += a.z * b.w;
            acc[3][0] += a.w * b.x; acc[3][1] += a.w * b.y; acc[3][2] += a.w * b.z; acc[3][3] += a.w * b.w;
        }
    }

    const int row0 = by * 64 + trow * 4;
    const int col0 = bx * 64 + tcol * 4;
    if (!TRANS_OUT) {
#pragma unroll
        for (int m = 0; m < 4; ++m) {
            float4 o = make_float4(acc[m][0], acc[m][1], acc[m][2], acc[m][3]);
            *(float4*)&C[(size_t)(row0 + m) * N + col0] = o;
        }
    } else {
#pragma unroll
        for (int n = 0; n < 4; ++n) {
            float4 o = make_float4(acc[0][n], acc[1][n], acc[2][n], acc[3][n]);
            *(float4*)&C[(size_t)(col0 + n) * M + row0] = o;
        }
    }
}

// ---------------------------------------------------------------------------
// Hidden-layer integrate-and-fire: one thread per neuron, sequential over
// 512 batches x 10 steps. cur layout [B][HID], rate layout [B][HID].
// ---------------------------------------------------------------------------
__global__ __launch_bounds__(256) void dyn_hidden_kernel(const float* __restrict__ cur,
                                                         float* __restrict__ rate) {
    int j = blockIdx.x * blockDim.x + threadIdx.x;
    if (j >= HID_DIM) return;
    float v = 0.f, thr = 1.0f, last = -INFINITY;
    int count = 0;
    float cn = cur[j];
    for (int b = 0; b < BATCH; ++b) {
        float c = cn;
        if (b + 1 < BATCH) cn = cur[(size_t)(b + 1) * HID_DIM + j];
        int s = 0;
#pragma unroll
        for (int t = 0; t < T_STEPS; ++t) {
            v = v * LEAK + c;
            float tt = (float)count;
            bool spike = (v >= thr) && (tt - last > 1.0f);
            if (spike) {
                last = tt;
                count += 1;
                v = 0.f;
                if (count > 10) thr += ADAPT;
                s += 1;
            }
        }
        rate[(size_t)b * HID_DIM + j] = s * 0.1f;
    }
}

// ---------------------------------------------------------------------------
// Output-layer integrate-and-fire: one thread per neuron (1024), current is
// stored transposed curT[OUT][BATCH] so each thread streams float4s.
// Writes d_out[B][OUT] (coalesced across threads).
// ---------------------------------------------------------------------------
__global__ __launch_bounds__(256) void dyn_out_kernel(const float* __restrict__ curT,
                                                      float* __restrict__ out) {
    int k = blockIdx.x * blockDim.x + threadIdx.x;
    if (k >= OUT_DIM) return;
    float v = 0.f, thr = 1.0f, last = -INFINITY;
    int count = 0;
    const float4* cp = (const float4*)(curT + (size_t)k * BATCH);
    float4 c4 = cp[0];
    for (int b4 = 0; b4 < BATCH / 4; ++b4) {
        float4 cc = c4;
        if (b4 + 1 < BATCH / 4) c4 = cp[b4 + 1];
        float cs[4] = {cc.x, cc.y, cc.z, cc.w};
#pragma unroll
        for (int i = 0; i < 4; ++i) {
            float c = cs[i];
            int s = 0;
#pragma unroll
            for (int t = 0; t < T_STEPS; ++t) {
                v = v * LEAK + c;
                float tt = (float)count;
                bool spike = (v >= thr) && (tt - last > 1.0f);
                if (spike) {
                    last = tt;
                    count += 1;
                    v = 0.f;
                    if (count > 10) thr += ADAPT;
                    s += 1;
                }
            }
            out[(size_t)(b4 * 4 + i) * OUT_DIM + k] = s * 0.1f;
        }
    }
}

// ---------------------------------------------------------------------------
extern "C" void kernel_launch(void* const* d_in, const int* in_sizes, int n_in,
                              void* d_out, int out_size, void* d_ws, size_t ws_size,
                              hipStream_t stream) {
    const float* x    = (const float*)d_in[0];  // [512, 4096]
    const float* W_ih = (const float*)d_in[1];  // [4096, 8192]
    const float* W_ho = (const float*)d_in[2];  // [8192, 1024]
    float* out = (float*)d_out;                 // [512, 1024]

    float* r_in   = (float*)d_ws;                       // 512*4096
    float* cur_h  = r_in + (size_t)BATCH * IN_DIM;      // 512*8192
    float* h_rate = cur_h + (size_t)BATCH * HID_DIM;    // 512*8192
    float* cur_oT = h_rate + (size_t)BATCH * HID_DIM;   // 1024*512 (transposed)

    // 1) input spike rates (expected value of the bernoulli rate code)
    int n4 = BATCH * IN_DIM / 4;
    rates_kernel<<<(n4 + 255) / 256, 256, 0, stream>>>(x, r_in, n4);

    // 2) cur_h = r_in @ W_ih   [512, 8192]
    dim3 g1(HID_DIM / 64, BATCH / 64);
    gemm_f32<false><<<g1, 256, 0, stream>>>(r_in, W_ih, cur_h, BATCH, HID_DIM, IN_DIM);

    // 3) hidden dynamics -> h_rate [512, 8192]
    dyn_hidden_kernel<<<HID_DIM / 256, 256, 0, stream>>>(cur_h, h_rate);

    // 4) cur_oT = (h_rate @ W_ho)^T   [1024, 512]
    dim3 g2(OUT_DIM / 64, BATCH / 64);
    gemm_f32<true><<<g2, 256, 0, stream>>>(h_rate, W_ho, cur_oT, BATCH, OUT_DIM, HID_DIM);

    // 5) output dynamics -> out [512, 1024]
    dyn_out_kernel<<<OUT_DIM / 256, 256, 0, stream>>>(cur_oT, out);
}

// Round 2
// 411.715 us; speedup vs baseline: 4.1656x; 4.1656x over previous
//
#include <hip/hip_runtime.h>
#include <hip/hip_bf16.h>
#include <math.h>

#define BATCH   512
#define IN_DIM  4096
#define HID_DIM 8192
#define OUT_DIM 1024
#define T_STEPS 10
#define LEAK    0.95f

typedef __attribute__((ext_vector_type(8))) short bf16x8;
typedef __attribute__((ext_vector_type(4))) float floatx4;

#define GLB_AS __attribute__((address_space(1)))
#define LDS_AS __attribute__((address_space(3)))

// async 16B/lane global->LDS: lds dest = wave-uniform base + lane*16
#define ASYNC_COPY16(gp, lp)                                                  \
    __builtin_amdgcn_global_load_lds((const GLB_AS unsigned int*)(gp),        \
                                     (LDS_AS unsigned int*)(lp), 16, 0, 0)

__device__ __forceinline__ unsigned short f2bf(float f) {
    unsigned int u = __float_as_uint(f);
    u += 0x7fffu + ((u >> 16) & 1u);   // RNE
    return (unsigned short)(u >> 16);
}

// ---------------------------------------------------------------------------
// r = bf16(sigmoid(x)), 4 elems/thread
// ---------------------------------------------------------------------------
__global__ __launch_bounds__(256) void rates_bf16(const float* __restrict__ x,
                                                  unsigned short* __restrict__ r, int n4) {
    int i = blockIdx.x * blockDim.x + threadIdx.x;
    if (i >= n4) return;
    float4 v = ((const float4*)x)[i];
    ushort4 o;
    o.x = f2bf(1.f / (1.f + __expf(-v.x)));
    o.y = f2bf(1.f / (1.f + __expf(-v.y)));
    o.z = f2bf(1.f / (1.f + __expf(-v.z)));
    o.w = f2bf(1.f / (1.f + __expf(-v.w)));
    ((ushort4*)r)[i] = o;
}

// ---------------------------------------------------------------------------
// transpose + convert: in fp32 [K][N] -> out bf16 [N][K]; 64x64 tiles
// ---------------------------------------------------------------------------
__global__ __launch_bounds__(256) void transpose_cvt(const float* __restrict__ in,
                                                     unsigned short* __restrict__ out,
                                                     int K, int N) {
    __shared__ float tile[64][65];  // +1 pad: conflict-free column reads
    const int nb = blockIdx.x * 64;
    const int kb = blockIdx.y * 64;
    const int t = threadIdx.x;
    const int tr = t >> 4;          // 0..15
    const int tc4 = (t & 15) * 4;   // 0..60
#pragma unroll
    for (int it = 0; it < 4; ++it) {
        int k = tr + 16 * it;
        float4 v = *(const float4*)&in[(size_t)(kb + k) * N + nb + tc4];
        tile[k][tc4 + 0] = v.x;
        tile[k][tc4 + 1] = v.y;
        tile[k][tc4 + 2] = v.z;
        tile[k][tc4 + 3] = v.w;
    }
    __syncthreads();
#pragma unroll
    for (int it = 0; it < 4; ++it) {
        int n = tr + 16 * it;
        ushort4 o;
        o.x = f2bf(tile[tc4 + 0][n]);
        o.y = f2bf(tile[tc4 + 1][n]);
        o.z = f2bf(tile[tc4 + 2][n]);
        o.w = f2bf(tile[tc4 + 3][n]);
        *(ushort4*)&out[(size_t)(nb + n) * K + kb + tc4] = o;
    }
}

// ---------------------------------------------------------------------------
// bf16 MFMA GEMM (m97 structure): C[M,N] = A[M,K] @ Bt[N,K]^T
// 128x128 tile, BK=32, 256 threads (4 waves, each a 64x64 quadrant of 4x4
// 16x16x32 MFMAs), global_load_lds width-16 staging.
// SPLITK>1: blockIdx.z owns K/SPLITK slice, epilogue atomicAdd (C pre-zeroed).
// ---------------------------------------------------------------------------
template <int SPLITK, bool ATOMIC>
__global__ __launch_bounds__(256) void gemm_bf16(const unsigned short* __restrict__ A,
                                                 const unsigned short* __restrict__ Bt,
                                                 float* __restrict__ C,
                                                 int M, int N, int K) {
    __shared__ unsigned short As[128 * 32];
    __shared__ unsigned short Bs[128 * 32];

    const int tid = threadIdx.x;
    const int wave = tid >> 6;
    const int lane = tid & 63;
    const int wr = wave >> 1;      // wave m-quadrant
    const int wc = wave & 1;       // wave n-quadrant

    const int m0 = blockIdx.y * 128;
    const int n0 = blockIdx.x * 128;
    const int Kseg = K / SPLITK;
    const int kb = blockIdx.z * Kseg;

    // staging: each wave issues 2 A-chunks + 2 B-chunks of 16 rows x 32 cols
    const int lr = lane >> 2;         // 0..15 (row within 16-row chunk)
    const int lc = (lane & 3) * 8;    // 0,8,16,24 (col)
    const unsigned short* agp = A + (size_t)(m0 + wave * 32 + lr) * K + kb + lc;
    const unsigned short* bgp = Bt + (size_t)(n0 + wave * 32 + lr) * K + kb + lc;
    unsigned short* asl0 = &As[(wave * 32) * 32];
    unsigned short* asl1 = &As[(wave * 32 + 16) * 32];
    unsigned short* bsl0 = &Bs[(wave * 32) * 32];
    unsigned short* bsl1 = &Bs[(wave * 32 + 16) * 32];

    const int fr = lane & 15;      // fragment row/col within 16
    const int fq = lane >> 4;      // quad -> k-offset fq*8
    floatx4 acc[4][4] = {};

    for (int k0 = 0; k0 < Kseg; k0 += 32) {
        __syncthreads();   // previous iter's ds_reads done before overwrite
        ASYNC_COPY16(agp, asl0);
        ASYNC_COPY16(agp + (size_t)16 * K, asl1);
        ASYNC_COPY16(bgp, bsl0);
        ASYNC_COPY16(bgp + (size_t)16 * K, bsl1);
        agp += 32;
        bgp += 32;
        __syncthreads();   // staging complete

        bf16x8 af[4], bfr[4];
#pragma unroll
        for (int i = 0; i < 4; ++i)
            af[i] = *(const bf16x8*)&As[(wr * 64 + i * 16 + fr) * 32 + fq * 8];
#pragma unroll
        for (int j = 0; j < 4; ++j)
            bfr[j] = *(const bf16x8*)&Bs[(wc * 64 + j * 16 + fr) * 32 + fq * 8];
#pragma unroll
        for (int i = 0; i < 4; ++i)
#pragma unroll
            for (int j = 0; j < 4; ++j)
                acc[i][j] = __builtin_amdgcn_mfma_f32_16x16x32_bf16(af[i], bfr[j], acc[i][j], 0, 0, 0);
    }

    // epilogue: C/D layout col=lane&15, row=(lane>>4)*4+reg  [m89-verified]
#pragma unroll
    for (int i = 0; i < 4; ++i) {
#pragma unroll
        for (int j = 0; j < 4; ++j) {
            int row = m0 + wr * 64 + i * 16 + fq * 4;
            int col = n0 + wc * 64 + j * 16 + fr;
#pragma unroll
            for (int r = 0; r < 4; ++r) {
                if (ATOMIC)
                    atomicAdd(&C[(size_t)(row + r) * N + col], acc[i][j][r]);
                else
                    C[(size_t)(row + r) * N + col] = acc[i][j][r];
            }
        }
    }
}

// ---------------------------------------------------------------------------
// Integrate-and-fire scan. Exact structural reduction (data-independent):
// with REFRACT=1 and t=spike_count, after any first spike t-last==1 which is
// never > 1 => each neuron fires at most once; count>10 adaptation
// unreachable; post-spike v never observable. So: fire on first v>=1 crossing
// of the pure leaky integration, then only zeros. Worst case (never fires)
// still simulates every step faithfully.
// ---------------------------------------------------------------------------
__global__ __launch_bounds__(256) void dyn_hidden(const float* __restrict__ cur,
                                                  unsigned short* __restrict__ rate) {
    int j = blockIdx.x * blockDim.x + threadIdx.x;
    const unsigned short one_tenth = f2bf(0.1f);
    float v = 0.f;
    bool fired = false;
    bool allfired = false;
    for (int b = 0; b < BATCH; ++b) {
        unsigned short s = 0;
        if (!allfired) {
            float c = cur[(size_t)b * HID_DIM + j];
            if (!fired) {
#pragma unroll
                for (int t = 0; t < T_STEPS; ++t) {
                    v = v * LEAK + c;
                    if (!fired && v >= 1.0f) { fired = true; s = one_tenth; }
                }
            }
            allfired = __all((int)fired);
        }
        rate[(size_t)b * HID_DIM + j] = s;
    }
}

__global__ __launch_bounds__(256) void dyn_out(const float* __restrict__ cur,
                                               float* __restrict__ out) {
    int j = blockIdx.x * blockDim.x + threadIdx.x;
    float v = 0.f;
    bool fired = false;
    bool allfired = false;
    for (int b = 0; b < BATCH; ++b) {
        float s = 0.f;
        if (!allfired) {
            float c = cur[(size_t)b * OUT_DIM + j];
            if (!fired) {
#pragma unroll
                for (int t = 0; t < T_STEPS; ++t) {
                    v = v * LEAK + c;
                    if (!fired && v >= 1.0f) { fired = true; s = 0.1f; }
                }
            }
            allfired = __all((int)fired);
        }
        out[(size_t)b * OUT_DIM + j] = s;
    }
}

__global__ __launch_bounds__(256) void zero_kernel(float* __restrict__ p, int n) {
    int i = blockIdx.x * blockDim.x + threadIdx.x;
    if (i < n) p[i] = 0.f;
}

// ---------------------------------------------------------------------------
extern "C" void kernel_launch(void* const* d_in, const int* in_sizes, int n_in,
                              void* d_out, int out_size, void* d_ws, size_t ws_size,
                              hipStream_t stream) {
    const float* x    = (const float*)d_in[0];  // [512, 4096]
    const float* W_ih = (const float*)d_in[1];  // [4096, 8192]
    const float* W_ho = (const float*)d_in[2];  // [8192, 1024]
    float* out = (float*)d_out;                 // [512, 1024] fp32

    char* base = (char*)d_ws;
    float*          cur_h  = (float*)(base + 0);                   // 16.8 MB
    unsigned short* r_bf   = (unsigned short*)(base + 16777216);   //  4.2 MB
    float*          cur_o  = (float*)(base + 20971520);            //  2.1 MB
    unsigned short* h_rate = (unsigned short*)(base + 23068672);   //  8.4 MB
    unsigned short* Wt1    = (unsigned short*)(base + 31457280);   // 67.1 MB
    unsigned short* Wt2    = Wt1;  // reuse: GEMM1 (reads Wt1) precedes transpose of W_ho

    // 1) input rates -> bf16 [512][4096]
    int n4 = BATCH * IN_DIM / 4;
    rates_bf16<<<n4 / 256, 256, 0, stream>>>(x, r_bf, n4);

    // 2) Wt1 = bf16(W_ih^T)  [8192][4096]
    transpose_cvt<<<dim3(HID_DIM / 64, IN_DIM / 64), 256, 0, stream>>>(W_ih, Wt1, IN_DIM, HID_DIM);

    // 3) cur_h = r_bf @ Wt1^T   [512][8192]
    gemm_bf16<1, false><<<dim3(HID_DIM / 128, BATCH / 128, 1), 256, 0, stream>>>(
        r_bf, Wt1, cur_h, BATCH, HID_DIM, IN_DIM);

    // 4) hidden dynamics -> h_rate bf16 [512][8192]
    dyn_hidden<<<HID_DIM / 256, 256, 0, stream>>>(cur_h, h_rate);

    // 5) Wt2 = bf16(W_ho^T)  [1024][8192]  (reuses Wt1 space)
    transpose_cvt<<<dim3(OUT_DIM / 64, HID_DIM / 64), 256, 0, stream>>>(W_ho, Wt2, HID_DIM, OUT_DIM);

    // 6) cur_o = 0, then split-K GEMM with atomic accumulate  [512][1024]
    zero_kernel<<<(BATCH * OUT_DIM) / 256, 256, 0, stream>>>(cur_o, BATCH * OUT_DIM);
    gemm_bf16<8, true><<<dim3(OUT_DIM / 128, BATCH / 128, 8), 256, 0, stream>>>(
        h_rate, Wt2, cur_o, BATCH, OUT_DIM, HID_DIM);

    // 7) output dynamics -> d_out fp32 [512][1024]
    dyn_out<<<OUT_DIM / 256, 256, 0, stream>>>(cur_o, out);
}

// Round 3
// 344.807 us; speedup vs baseline: 4.9739x; 1.1940x over previous
//
#include <hip/hip_runtime.h>
#include <hip/hip_bf16.h>
#include <math.h>

#define BATCH   512
#define IN_DIM  4096
#define HID_DIM 8192
#define OUT_DIM 1024
#define T_STEPS 10
#define LEAK    0.95f

typedef __attribute__((ext_vector_type(8))) short bf16x8;
typedef __attribute__((ext_vector_type(4))) float floatx4;

#define GLB_AS __attribute__((address_space(1)))
#define LDS_AS __attribute__((address_space(3)))

// async 16B/lane global->LDS: lds dest = wave-uniform base + lane*16
#define ASYNC_COPY16(gp, lp)                                                  \
    __builtin_amdgcn_global_load_lds((const GLB_AS unsigned int*)(gp),        \
                                     (LDS_AS unsigned int*)(lp), 16, 0, 0)

__device__ __forceinline__ unsigned short f2bf(float f) {
    unsigned int u = __float_as_uint(f);
    u += 0x7fffu + ((u >> 16) & 1u);   // RNE
    return (unsigned short)(u >> 16);
}

// ---------------------------------------------------------------------------
// r = bf16(sigmoid(x)), 4 elems/thread
// ---------------------------------------------------------------------------
__global__ __launch_bounds__(256) void rates_bf16(const float* __restrict__ x,
                                                  unsigned short* __restrict__ r, int n4) {
    int i = blockIdx.x * blockDim.x + threadIdx.x;
    if (i >= n4) return;
    float4 v = ((const float4*)x)[i];
    ushort4 o;
    o.x = f2bf(1.f / (1.f + __expf(-v.x)));
    o.y = f2bf(1.f / (1.f + __expf(-v.y)));
    o.z = f2bf(1.f / (1.f + __expf(-v.z)));
    o.w = f2bf(1.f / (1.f + __expf(-v.w)));
    ((ushort4*)r)[i] = o;
}

// ---------------------------------------------------------------------------
// transpose + convert: in fp32 [K][N] -> out bf16 [N][K]; 64x64 tiles
// ---------------------------------------------------------------------------
__global__ __launch_bounds__(256) void transpose_cvt(const float* __restrict__ in,
                                                     unsigned short* __restrict__ out,
                                                     int K, int N) {
    __shared__ float tile[64][65];
    const int nb = blockIdx.x * 64;
    const int kb = blockIdx.y * 64;
    const int t = threadIdx.x;
    const int tr = t >> 4;
    const int tc4 = (t & 15) * 4;
#pragma unroll
    for (int it = 0; it < 4; ++it) {
        int k = tr + 16 * it;
        float4 v = *(const float4*)&in[(size_t)(kb + k) * N + nb + tc4];
        tile[k][tc4 + 0] = v.x;
        tile[k][tc4 + 1] = v.y;
        tile[k][tc4 + 2] = v.z;
        tile[k][tc4 + 3] = v.w;
    }
    __syncthreads();
#pragma unroll
    for (int it = 0; it < 4; ++it) {
        int n = tr + 16 * it;
        ushort4 o;
        o.x = f2bf(tile[tc4 + 0][n]);
        o.y = f2bf(tile[tc4 + 1][n]);
        o.z = f2bf(tile[tc4 + 2][n]);
        o.w = f2bf(tile[tc4 + 3][n]);
        *(ushort4*)&out[(size_t)(nb + n) * K + kb + tc4] = o;
    }
}

// ---------------------------------------------------------------------------
// bf16 MFMA GEMM: C[M,N] = A[M,K] @ Bt[N,K]^T
// 128M x 64N tile, BK=32, 256 threads = 4 waves in 2x2 quadrants of 64x32.
// Per wave: 4x2 frags of 16x16x32. SPLITK>1: blockIdx.z owns K/SPLITK slice,
// writes PLAIN stores to partial buffer C + z*M*N (no atomics).
// ---------------------------------------------------------------------------
template <int SPLITK>
__global__ __launch_bounds__(256) void gemm_bf16(const unsigned short* __restrict__ A,
                                                 const unsigned short* __restrict__ Bt,
                                                 float* __restrict__ C,
                                                 int M, int N, int K) {
    __shared__ unsigned short As[128 * 32];
    __shared__ unsigned short Bs[64 * 32];

    const int tid = threadIdx.x;
    const int wave = tid >> 6;
    const int lane = tid & 63;
    const int wr = wave >> 1;      // M half (64 rows)
    const int wc = wave & 1;       // N half (32 cols)

    const int m0 = blockIdx.y * 128;
    const int n0 = blockIdx.x * 64;
    const int Kseg = K / SPLITK;
    const int kb = blockIdx.z * Kseg;

    const int lr = lane >> 2;         // 0..15
    const int lc = (lane & 3) * 8;    // 0,8,16,24
    const unsigned short* agp = A + (size_t)(m0 + wave * 32 + lr) * K + kb + lc;
    const unsigned short* bgp = Bt + (size_t)(n0 + wave * 16 + lr) * K + kb + lc;
    unsigned short* asl0 = &As[(wave * 32) * 32];
    unsigned short* asl1 = &As[(wave * 32 + 16) * 32];
    unsigned short* bsl  = &Bs[(wave * 16) * 32];

    const int fr = lane & 15;
    const int fq = lane >> 4;
    floatx4 acc[4][2] = {};

    for (int k0 = 0; k0 < Kseg; k0 += 32) {
        __syncthreads();
        ASYNC_COPY16(agp, asl0);
        ASYNC_COPY16(agp + (size_t)16 * K, asl1);
        ASYNC_COPY16(bgp, bsl);
        agp += 32;
        bgp += 32;
        __syncthreads();

        bf16x8 af[4], bfr[2];
#pragma unroll
        for (int i = 0; i < 4; ++i)
            af[i] = *(const bf16x8*)&As[(wr * 64 + i * 16 + fr) * 32 + fq * 8];
#pragma unroll
        for (int j = 0; j < 2; ++j)
            bfr[j] = *(const bf16x8*)&Bs[(wc * 32 + j * 16 + fr) * 32 + fq * 8];
#pragma unroll
        for (int i = 0; i < 4; ++i)
#pragma unroll
            for (int j = 0; j < 2; ++j)
                acc[i][j] = __builtin_amdgcn_mfma_f32_16x16x32_bf16(af[i], bfr[j], acc[i][j], 0, 0, 0);
    }

    float* Cp = C + (size_t)blockIdx.z * M * N;
#pragma unroll
    for (int i = 0; i < 4; ++i) {
#pragma unroll
        for (int j = 0; j < 2; ++j) {
            int row = m0 + wr * 64 + i * 16 + fq * 4;
            int col = n0 + wc * 32 + j * 16 + fr;
#pragma unroll
            for (int r = 0; r < 4; ++r)
                Cp[(size_t)(row + r) * N + col] = acc[i][j][r];
        }
    }
}

// ---------------------------------------------------------------------------
// First-spike scan (exact structural reduction: REFRACT=1 & t=spike_count =>
// each neuron spikes at most once ever; adaptation unreachable). Finds the
// batch index of the single spike (or -1). NPART partial buffers are summed.
// Wave-level early exit once all lanes fired.
// ---------------------------------------------------------------------------
template <int NPART>
__global__ __launch_bounds__(256) void first_spike(const float* __restrict__ cur,
                                                   int* __restrict__ b_fire, int n) {
    int j = blockIdx.x * blockDim.x + threadIdx.x;
    float v = 0.f;
    bool fired = false;
    int bf = -1;
    for (int b = 0; b < BATCH; ++b) {
        float c = 0.f;
#pragma unroll
        for (int z = 0; z < NPART; ++z)
            c += cur[(size_t)z * BATCH * n + (size_t)b * n + j];
#pragma unroll
        for (int t = 0; t < T_STEPS; ++t) {
            v = v * LEAK + c;
            if (!fired && v >= 1.0f) { fired = true; bf = b; }
        }
        if (__all((int)fired)) break;
    }
    b_fire[j] = bf;
}

// rate[b][j] = (b_fire[j]==b) ? 0.1 : 0, bf16, 4 elems/thread, wide grid
__global__ __launch_bounds__(256) void write_rate_bf16(const int* __restrict__ b_fire,
                                                       unsigned short* __restrict__ rate) {
    int gid = blockIdx.x * blockDim.x + threadIdx.x;       // over B*HID/4
    int b = gid >> 11;                                     // HID/4 = 2048
    int j = (gid & 2047) << 2;
    int4 bf = *(const int4*)&b_fire[j];
    const unsigned short ot = f2bf(0.1f);
    ushort4 o;
    o.x = (bf.x == b) ? ot : 0;
    o.y = (bf.y == b) ? ot : 0;
    o.z = (bf.z == b) ? ot : 0;
    o.w = (bf.w == b) ? ot : 0;
    *(ushort4*)&rate[(size_t)b * HID_DIM + j] = o;
}

// out[b][k] = (b_fire[k]==b) ? 0.1f : 0, fp32, 4 elems/thread
__global__ __launch_bounds__(256) void write_out_f32(const int* __restrict__ b_fire,
                                                     float* __restrict__ out) {
    int gid = blockIdx.x * blockDim.x + threadIdx.x;       // over B*OUT/4
    int b = gid >> 8;                                      // OUT/4 = 256
    int k = (gid & 255) << 2;
    int4 bf = *(const int4*)&b_fire[k];
    float4 o;
    o.x = (bf.x == b) ? 0.1f : 0.f;
    o.y = (bf.y == b) ? 0.1f : 0.f;
    o.z = (bf.z == b) ? 0.1f : 0.f;
    o.w = (bf.w == b) ? 0.1f : 0.f;
    *(float4*)&out[(size_t)b * OUT_DIM + k] = o;
}

// ---------------------------------------------------------------------------
extern "C" void kernel_launch(void* const* d_in, const int* in_sizes, int n_in,
                              void* d_out, int out_size, void* d_ws, size_t ws_size,
                              hipStream_t stream) {
    const float* x    = (const float*)d_in[0];  // [512, 4096]
    const float* W_ih = (const float*)d_in[1];  // [4096, 8192]
    const float* W_ho = (const float*)d_in[2];  // [8192, 1024]
    float* out = (float*)d_out;                 // [512, 1024] fp32

    char* base = (char*)d_ws;
    float*          cur_h   = (float*)(base + 0);                  // 16.8 MB; later cur_o parts (8 x 2 MB)
    unsigned short* r_bf    = (unsigned short*)(base + 16777216);  //  4.2 MB
    unsigned short* h_rate  = (unsigned short*)(base + 20971520);  //  8.4 MB
    int*            bfire_h = (int*)(base + 29360128);             //  32 KB
    int*            bfire_o = (int*)(base + 29392896);             //   4 KB
    unsigned short* Wt      = (unsigned short*)(base + 31457280);  // 67.1 MB (Wih^T, then Who^T)
    float*          cur_o   = cur_h;  // overlay: cur_h consumed by first_spike before GEMM2

    // 1) input rates -> bf16 [512][4096]
    int n4 = BATCH * IN_DIM / 4;
    rates_bf16<<<n4 / 256, 256, 0, stream>>>(x, r_bf, n4);

    // 2) Wt = bf16(W_ih^T)  [8192][4096]
    transpose_cvt<<<dim3(HID_DIM / 64, IN_DIM / 64), 256, 0, stream>>>(W_ih, Wt, IN_DIM, HID_DIM);

    // 3) cur_h = r_bf @ Wt^T  [512][8192]; 128x64 tiles -> 512 blocks
    gemm_bf16<1><<<dim3(HID_DIM / 64, BATCH / 128, 1), 256, 0, stream>>>(
        r_bf, Wt, cur_h, BATCH, HID_DIM, IN_DIM);

    // 4) hidden first-spike scan -> bfire_h [8192]
    first_spike<1><<<HID_DIM / 256, 256, 0, stream>>>(cur_h, bfire_h, HID_DIM);

    // 5) h_rate bf16 [512][8192] (wide, coalesced)
    write_rate_bf16<<<(BATCH * HID_DIM / 4) / 256, 256, 0, stream>>>(bfire_h, h_rate);

    // 6) Wt = bf16(W_ho^T)  [1024][8192] (overwrites)
    transpose_cvt<<<dim3(OUT_DIM / 64, HID_DIM / 64), 256, 0, stream>>>(W_ho, Wt, HID_DIM, OUT_DIM);

    // 7) cur_o partials: split-K=8, plain stores -> 8 x [512][1024]; 512 blocks
    gemm_bf16<8><<<dim3(OUT_DIM / 64, BATCH / 128, 8), 256, 0, stream>>>(
        h_rate, Wt, cur_o, BATCH, OUT_DIM, HID_DIM);

    // 8) output first-spike scan (sums 8 partials) -> bfire_o [1024]
    first_spike<8><<<OUT_DIM / 256, 256, 0, stream>>>(cur_o, bfire_o, OUT_DIM);

    // 9) d_out [512][1024] fp32 (wide, coalesced)
    write_out_f32<<<(BATCH * OUT_DIM / 4) / 256, 256, 0, stream>>>(bfire_o, out);
}